// Round 1
// baseline (39.275 us; speedup 1.0000x reference)
//
#include <hip/hip_runtime.h>

#define PI_OVER_4 0.78539816339744830962f

__device__ __forceinline__ float lane_sign(int m) {
    return (__popc(m) & 1) ? -1.0f : 1.0f;
}

// 8 lanes per sample. Basis index s (8 bits, qubit q <-> bit 7-q):
//   lane slot sl = s>>5 (qubits 0,1,2 on sl bits 2,1,0)
//   reg index r = s&31 (qubits 3..7 on r bits 4..0)
__global__ __launch_bounds__(256) void qsim8_kernel(
        const float* __restrict__ x, const float* __restrict__ w,
        float* __restrict__ out, int nsamples) {
    const int tid = blockIdx.x * blockDim.x + threadIdx.x;
    const int sample = tid >> 3;
    if (sample >= nsamples) return;
    const int lane = threadIdx.x & 63;
    const int sl = lane & 7;

    // ---- per-sample angles (all 8 lanes of the group load same 32B; broadcast) ----
    const float4* xv = reinterpret_cast<const float4*>(x + (size_t)sample * 8);
    const float4 xa = xv[0], xb = xv[1];
    const float xs[8] = {xa.x, xa.y, xa.z, xa.w, xb.x, xb.y, xb.z, xb.w};

    // ---- Layer 1: per-qubit complex factors: RY(x*pi/2 + w_ry) on |0>, then RZ(w_rz)
    float f0r[8], f0i[8], f1r[8], f1i[8];
#pragma unroll
    for (int q = 0; q < 8; ++q) {
        const float h = fmaf(xs[q], PI_OVER_4, 0.5f * w[2 * q + 0]);
        const float z = 0.5f * w[2 * q + 1];
        float sh, ch, sz, cz;
        __sincosf(h, &sh, &ch);
        __sincosf(z, &sz, &cz);
        f0r[q] = ch * cz;  f0i[q] = -ch * sz;   // alpha * e^{-i z}
        f1r[q] = sh * cz;  f1i[q] = sh * sz;    // beta  * e^{+i z}
    }

    // lane factor: product of qubit 0,1,2 factors selected by sl bits
    const int b0 = (sl >> 2) & 1, b1 = (sl >> 1) & 1, b2 = sl & 1;
    float Fr = b0 ? f1r[0] : f0r[0];
    float Fi = b0 ? f1i[0] : f0i[0];
    {
        const float gr = b1 ? f1r[1] : f0r[1], gi = b1 ? f1i[1] : f0i[1];
        const float tr = Fr * gr - Fi * gi;
        const float ti = Fr * gi + Fi * gr;
        const float hr = b2 ? f1r[2] : f0r[2], hi = b2 ? f1i[2] : f0i[2];
        Fr = tr * hr - ti * hi;
        Fi = tr * hi + ti * hr;
    }

    // expand product state over qubits 3..7 (log-doubling; qubit 3 ends at r bit 4)
    float re[32], im[32];
    re[0] = Fr; im[0] = Fi;
#define EXPAND(Q, M)                                   \
    _Pragma("unroll")                                  \
    for (int j = (M) - 1; j >= 0; --j) {               \
        const float a = re[j], b = im[j];              \
        re[2 * j + 1] = a * f1r[Q] - b * f1i[Q];       \
        im[2 * j + 1] = a * f1i[Q] + b * f1r[Q];       \
        re[2 * j]     = a * f0r[Q] - b * f0i[Q];       \
        im[2 * j]     = a * f0i[Q] + b * f0r[Q];       \
    }
    EXPAND(3, 1)
    EXPAND(4, 2)
    EXPAND(5, 4)
    EXPAND(6, 8)
    EXPAND(7, 16)
#undef EXPAND

    // ---- Layer 1 CNOT ring (explicit) ----
    // CNOT(0,1)+CNOT(1,2) combined: pure lane permutation.
    // dest sl bits (a,B,C): src = (a, B^a, C^B)
    {
        const int srcsl = (sl & 4) | ((((sl >> 1) ^ (sl >> 2)) & 1) << 1)
                        | ((sl ^ (sl >> 1)) & 1);
        const int srcLane = (lane & 56) | srcsl;
#pragma unroll
        for (int r = 0; r < 32; ++r) {
            re[r] = __shfl(re[r], srcLane);
            im[r] = __shfl(im[r], srcLane);
        }
    }
    // CNOT(2,3): ctrl = sl bit0, tgt = r bit4 (swap halves when ctrl set)
    {
        const bool c = (sl & 1) != 0;
#pragma unroll
        for (int r = 0; r < 16; ++r) {
            const float a = re[r], b = re[r + 16];
            re[r] = c ? b : a;  re[r + 16] = c ? a : b;
            const float ai = im[r], bi = im[r + 16];
            im[r] = c ? bi : ai;  im[r + 16] = c ? ai : bi;
        }
    }
    // CNOT(3,4): swap r bit3-pair where r bit4 = 1
#pragma unroll
    for (int r = 16; r < 24; ++r) {
        float t = re[r]; re[r] = re[r + 8]; re[r + 8] = t;
        t = im[r]; im[r] = im[r + 8]; im[r + 8] = t;
    }
    // CNOT(4,5)
#pragma unroll
    for (int r = 0; r < 32; ++r) {
        if ((r & 12) == 8) {
            float t = re[r]; re[r] = re[r + 4]; re[r + 4] = t;
            t = im[r]; im[r] = im[r + 4]; im[r + 4] = t;
        }
    }
    // CNOT(5,6)
#pragma unroll
    for (int r = 0; r < 32; ++r) {
        if ((r & 6) == 4) {
            float t = re[r]; re[r] = re[r + 2]; re[r + 2] = t;
            t = im[r]; im[r] = im[r + 2]; im[r + 2] = t;
        }
    }
    // CNOT(6,7)
#pragma unroll
    for (int r = 0; r < 32; ++r) {
        if ((r & 3) == 2) {
            float t = re[r]; re[r] = re[r + 1]; re[r + 1] = t;
            t = im[r]; im[r] = im[r + 1]; im[r + 1] = t;
        }
    }
    // CNOT(7,0): ctrl = r bit0, tgt = sl bit2 -> exchange odd-r amps across sl^4
#pragma unroll
    for (int r = 1; r < 32; r += 2) {
        re[r] = __shfl_xor(re[r], 4);
        im[r] = __shfl_xor(im[r], 4);
    }

    // ---- Layer 2: fused RY(x*pi/2 + w_ry) per qubit.
    // RZ dropped (pure phase before measurement); CNOT ring folded into masks.
    float c2[8], s2[8];
#pragma unroll
    for (int q = 0; q < 8; ++q) {
        const float h = fmaf(xs[q], PI_OVER_4, 0.5f * w[16 + 2 * q]);
        __sincosf(h, &s2[q], &c2[q]);
    }
    // lane-bit qubits 0,1,2
#pragma unroll
    for (int q = 0; q < 3; ++q) {
        const int mask = 4 >> q;
        const int bit = (sl >> (2 - q)) & 1;
        const float cc = c2[q];
        const float sg = bit ? s2[q] : -s2[q];
#pragma unroll
        for (int r = 0; r < 32; ++r) {
            float o = __shfl_xor(re[r], mask);
            re[r] = fmaf(sg, o, cc * re[r]);
            o = __shfl_xor(im[r], mask);
            im[r] = fmaf(sg, o, cc * im[r]);
        }
    }
    // reg-bit qubits 3..7
#pragma unroll
    for (int q = 3; q < 8; ++q) {
        const int stride = 1 << (7 - q);
        const float cc = c2[q], ss = s2[q];
#pragma unroll
        for (int r = 0; r < 32; ++r) {
            if ((r & stride) == 0) {
                const float a = re[r], b = re[r + stride];
                re[r] = cc * a - ss * b;
                re[r + stride] = ss * a + cc * b;
                const float ai = im[r], bi = im[r + stride];
                im[r] = cc * ai - ss * bi;
                im[r + stride] = ss * ai + cc * bi;
            }
        }
    }

    // ---- Measurement: <Z_i> = sum_s p(s) * (-1)^{parity(s & V_i)} with
    // V_i = rows of the CNOT-ring GF(2) map:
    // V (s-bit masks): 0x7F,0xC0,0xE0,0xF0,0xF8,0xFC,0xFE,0xFF
    // reg parts: {0x1F,0,0,0x10,0x18,0x1C,0x1E,0x1F}; sl parts: {3,6,7,7,7,7,7,7}
    float s00 = 0.f, s1F = 0.f, s10 = 0.f, s18 = 0.f, s1C = 0.f, s1E = 0.f;
#pragma unroll
    for (int r = 0; r < 32; ++r) {
        const float p = re[r] * re[r] + im[r] * im[r];
        s00 += p;
        s1F += (__builtin_popcount(r & 0x1F) & 1) ? -p : p;
        s10 += ((r >> 4) & 1) ? -p : p;
        s18 += (__builtin_popcount(r & 0x18) & 1) ? -p : p;
        s1C += (__builtin_popcount(r & 0x1C) & 1) ? -p : p;
        s1E += (__builtin_popcount(r & 0x1E) & 1) ? -p : p;
    }
    const float g7 = lane_sign(sl & 7);
    float acc0 = s1F * lane_sign(sl & 3);
    float acc1 = s00 * lane_sign(sl & 6);
    float acc2 = s00 * g7;
    float acc3 = s10 * g7;
    float acc4 = s18 * g7;
    float acc5 = s1C * g7;
    float acc6 = s1E * g7;
    float acc7 = s1F * g7;

#define RED(v) v += __shfl_xor(v, 1); v += __shfl_xor(v, 2); v += __shfl_xor(v, 4);
    RED(acc0) RED(acc1) RED(acc2) RED(acc3)
    RED(acc4) RED(acc5) RED(acc6) RED(acc7)
#undef RED

    float vout = acc0;
    vout = (sl == 1) ? acc1 : vout;
    vout = (sl == 2) ? acc2 : vout;
    vout = (sl == 3) ? acc3 : vout;
    vout = (sl == 4) ? acc4 : vout;
    vout = (sl == 5) ? acc5 : vout;
    vout = (sl == 6) ? acc6 : vout;
    vout = (sl == 7) ? acc7 : vout;
    out[(size_t)sample * 8 + sl] = vout;
}

extern "C" void kernel_launch(void* const* d_in, const int* in_sizes, int n_in,
                              void* d_out, int out_size, void* d_ws, size_t ws_size,
                              hipStream_t stream) {
    const float* x = (const float*)d_in[0];
    const float* w = (const float*)d_in[1];
    float* outp = (float*)d_out;
    const int nsamples = in_sizes[0] / 8;
    const int nthreads = nsamples * 8;
    const int block = 256;
    const int grid = (nthreads + block - 1) / block;
    qsim8_kernel<<<grid, block, 0, stream>>>(x, w, outp, nsamples);
}

// Round 2
// 28.439 us; speedup vs baseline: 1.3810x; 1.3810x over previous
//
#include <hip/hip_runtime.h>

typedef float v2f __attribute__((ext_vector_type(2)));

#define PI_OVER_4 0.78539816339744830962f

__device__ __forceinline__ v2f fma2(v2f a, v2f b, v2f c) { return __builtin_elementwise_fma(a, b, c); }
__device__ __forceinline__ v2f splat(float s) { v2f r; r.x = s; r.y = s; return r; }
__device__ __forceinline__ v2f shflx(v2f v, int m) {
    v2f r; r.x = __shfl_xor(v.x, m); r.y = __shfl_xor(v.y, m); return r;
}

// Storage in pre-L1-ring coordinates t (qubit q <-> t_q):
//   lane slot sl bits (2,1,0) = (t0,t1,t2); reg r bits (4..0) = (t3..t7).
// L1 ring s = P(t) is folded into gate masks M_q = P^{-1}(e_q) and
// measurement masks C_i = XOR_{q in R_i} R_q (R_q = rows of P).
__global__ __launch_bounds__(256) void qsim8_kernel(
        const float* __restrict__ x, const float* __restrict__ w,
        float* __restrict__ out, int nsamples) {
    const int tid = blockIdx.x * blockDim.x + threadIdx.x;
    const int sample = tid >> 3;
    if (sample >= nsamples) return;
    const int sl = threadIdx.x & 7;

    const float4* xv = reinterpret_cast<const float4*>(x + (size_t)sample * 8);
    const float4 xa = xv[0], xb = xv[1];
    const float xs[8] = {xa.x, xa.y, xa.z, xa.w, xb.x, xb.y, xb.z, xb.w};

    // ---- Layer 1 per-qubit factors: RY(x*pi/2 + w_ry) then RZ(w_rz) on |0>
    // f0 = (chcz, -chsz), f1 = (shcz, shsz)
    float chcz[8], chsz[8], shcz[8], shsz[8];
#pragma unroll
    for (int q = 0; q < 8; ++q) {
        const float h = fmaf(xs[q], PI_OVER_4, 0.5f * w[2 * q]);
        const float zz = 0.5f * w[2 * q + 1];
        float sh, ch, sz, cz;
        __sincosf(h, &sh, &ch);
        __sincosf(zz, &sz, &cz);
        chcz[q] = ch * cz; chsz[q] = ch * sz;
        shcz[q] = sh * cz; shsz[q] = sh * sz;
    }

    // ---- lane factor: qubits 0,1,2 selected by sl bits 2,1,0
    float Fr, Fi;
    {
        const int b0 = (sl >> 2) & 1, b1 = (sl >> 1) & 1, b2 = sl & 1;
        Fr = b0 ? shcz[0] : chcz[0];
        Fi = b0 ? shsz[0] : -chsz[0];
        const float g1r = b1 ? shcz[1] : chcz[1];
        const float g1i = b1 ? shsz[1] : -chsz[1];
        const float tr = Fr * g1r - Fi * g1i;
        const float ti = Fr * g1i + Fi * g1r;
        const float g2r = b2 ? shcz[2] : chcz[2];
        const float g2i = b2 ? shsz[2] : -chsz[2];
        Fr = tr * g2r - ti * g2i;
        Fi = tr * g2i + ti * g2r;
    }

    // ---- expand product state over qubits 3..7 (r bit4=t3 ... bit0=t7)
    v2f z[32];
    z[0].x = Fr; z[0].y = Fi;
#define EXPAND(Q, M)                                                      \
    {                                                                     \
        const v2f e0  = {chcz[Q], -chsz[Q]};                              \
        const v2f e0f = {chsz[Q],  chcz[Q]};                              \
        const v2f e1  = {shcz[Q],  shsz[Q]};                              \
        const v2f e1f = {-shsz[Q], shcz[Q]};                              \
        _Pragma("unroll")                                                 \
        for (int j = (M) - 1; j >= 0; --j) {                              \
            const v2f a = z[j];                                           \
            z[2 * j + 1] = fma2(splat(a.x), e1, splat(a.y) * e1f);        \
            z[2 * j]     = fma2(splat(a.x), e0, splat(a.y) * e0f);        \
        }                                                                 \
    }
    EXPAND(3, 1)
    EXPAND(4, 2)
    EXPAND(5, 4)
    EXPAND(6, 8)
    EXPAND(7, 16)
#undef EXPAND

    // ---- Layer 2 fused RY(x*pi/2 + w_ry) angles (RZ dropped; L2 ring folded into masks)
    float c2[8], s2[8];
#pragma unroll
    for (int q = 0; q < 8; ++q) {
        const float h = fmaf(xs[q], PI_OVER_4, 0.5f * w[16 + 2 * q]);
        __sincosf(h, &s2[q], &c2[q]);
    }

    const int pl  = __popc(sl) & 1;       // t0^t1^t2
    const int p12 = __popc(sl & 3) & 1;   // t1^t2
    const int p01 = __popc(sl & 6) & 1;   // t0^t1

    // ---- fused gates qubit 0 (M={t0,t1}: lane^6) and qubit 7 (M={t0,t1,t7}: lane^6, r^1)
    // u0 = p12 ^ par(r); u7 = pl ^ par(r)
    {
        const float c0 = c2[0], c7 = c2[7];
        const float gr = p12 ? s2[0] : -s2[0];
        const float hr = pl ? s2[7] : -s2[7];
#pragma unroll
        for (int r = 0; r < 32; r += 2) {
            const float g = (__builtin_popcount(r) & 1) ? -gr : gr;
            const float h = (__builtin_popcount(r) & 1) ? -hr : hr;
            const v2f a = z[r], b = z[r + 1];
            const v2f c = shflx(a, 6);
            const v2f d = shflx(b, 6);
            const v2f a1 = fma2(splat(g),  c, splat(c0) * a);
            const v2f b1 = fma2(splat(-g), d, splat(c0) * b);
            const v2f c1 = fma2(splat(-g), a, splat(c0) * c);
            const v2f d1 = fma2(splat(g),  b, splat(c0) * d);
            z[r]     = fma2(splat(h),  d1, splat(c7) * a1);
            z[r + 1] = fma2(splat(-h), c1, splat(c7) * b1);
        }
    }
    // ---- gate qubit 1: M={t1,t2} -> lane^3; u1 = p01 (uniform over r)
    {
        const float cc = c2[1];
        const float g = p01 ? s2[1] : -s2[1];
#pragma unroll
        for (int r = 0; r < 32; ++r) {
            const v2f o = shflx(z[r], 3);
            z[r] = fma2(splat(g), o, splat(cc) * z[r]);
        }
    }
    // ---- gate qubit 2: M={t2,t3} -> lane^1, r^16; u2 = pl (uniform over r)
    {
        const float cc = c2[2];
        const float g = pl ? s2[2] : -s2[2];
#pragma unroll
        for (int r = 0; r < 16; ++r) {
            const v2f oA = shflx(z[r + 16], 1);
            const v2f oB = shflx(z[r], 1);
            z[r]      = fma2(splat(g), oA, splat(cc) * z[r]);
            z[r + 16] = fma2(splat(g), oB, splat(cc) * z[r + 16]);
        }
    }
    // ---- reg-local gates q=3..6: pair r ^ MR, sign = pl ^ par(r & RR)
#define REGGATE(Q, MR, HB, RR)                                                \
    {                                                                         \
        const float cc = c2[Q];                                               \
        const float g = pl ? s2[Q] : -s2[Q];                                  \
        _Pragma("unroll")                                                     \
        for (int r = 0; r < 32; ++r) {                                        \
            if ((r & (HB)) == 0) {                                            \
                const int rB = r ^ (MR);                                      \
                const float sA = (__builtin_popcount(r & (RR)) & 1) ? -g : g; \
                const v2f a = z[r], b = z[rB];                                \
                z[r]  = fma2(splat(sA),  b, splat(cc) * a);                   \
                z[rB] = fma2(splat(-sA), a, splat(cc) * b);                   \
            }                                                                 \
        }                                                                     \
    }
    REGGATE(3, 24, 16, 16)
    REGGATE(4, 12, 8, 24)
    REGGATE(5, 6, 4, 28)
    REGGATE(6, 3, 2, 30)
#undef REGGATE

    // ---- measurement: <Z_i> = sum_t p(t) (-1)^{par(t & C_i)}
    // C_i (lane mask | reg mask): C0=6|0x15 C1=5|0x1F C2=2|0x1F C3=5|0x0F
    //                             C4=2|0x17 C5=5|0x0B C6=2|0x15 C7=5|0x0A
    float p[32];
#pragma unroll
    for (int r = 0; r < 32; ++r) {
        const v2f q = z[r] * z[r];
        p[r] = q.x + q.y;
    }
    float s0F = 0.f, s0B = 0.f, s0A = 0.f, s15 = 0.f, s1F = 0.f, s17 = 0.f;
#pragma unroll
    for (int k = 0; k < 16; ++k) {
        const float uu = p[k] + p[k + 16];   // bit4 not in mask
        const float vv = p[k] - p[k + 16];   // bit4 in mask
        s0F += (__builtin_popcount(k & 0xF) & 1) ? -uu : uu;
        s0B += (__builtin_popcount(k & 0xB) & 1) ? -uu : uu;
        s0A += (__builtin_popcount(k & 0xA) & 1) ? -uu : uu;
        s15 += (__builtin_popcount(k & 0x5) & 1) ? -vv : vv;
        s1F += (__builtin_popcount(k & 0xF) & 1) ? -vv : vv;
        s17 += (__builtin_popcount(k & 0x7) & 1) ? -vv : vv;
    }
    const float A = p01 ? -1.f : 1.f;                  // par(sl&6)
    const float B = (__popc(sl & 5) & 1) ? -1.f : 1.f; // par(sl&5)
    const float D = (sl & 2) ? -1.f : 1.f;             // par(sl&2)
    float acc[8];
    acc[0] = A * s15;
    acc[1] = B * s1F;
    acc[2] = D * s1F;
    acc[3] = B * s0F;
    acc[4] = D * s17;
    acc[5] = B * s0B;
    acc[6] = D * s15;
    acc[7] = B * s0A;

    // ---- transpose-reduce: lane sl ends with sum over 8 lanes of acc[sl]
    const int hi = (sl >> 2) & 1, h1 = (sl >> 1) & 1, h0 = sl & 1;
    float bb[4];
#pragma unroll
    for (int k = 0; k < 4; ++k) {
        const float send = hi ? acc[k] : acc[k + 4];
        const float recv = __shfl_xor(send, 4);
        bb[k] = (hi ? acc[k + 4] : acc[k]) + recv;
    }
    float cc2[2];
#pragma unroll
    for (int k = 0; k < 2; ++k) {
        const float send = h1 ? bb[k] : bb[k + 2];
        const float recv = __shfl_xor(send, 2);
        cc2[k] = (h1 ? bb[k + 2] : bb[k]) + recv;
    }
    const float send = h0 ? cc2[0] : cc2[1];
    const float recv = __shfl_xor(send, 1);
    const float res = (h0 ? cc2[1] : cc2[0]) + recv;
    out[(size_t)sample * 8 + sl] = res;
}

extern "C" void kernel_launch(void* const* d_in, const int* in_sizes, int n_in,
                              void* d_out, int out_size, void* d_ws, size_t ws_size,
                              hipStream_t stream) {
    const float* x = (const float*)d_in[0];
    const float* w = (const float*)d_in[1];
    float* outp = (float*)d_out;
    const int nsamples = in_sizes[0] / 8;
    const int nthreads = nsamples * 8;
    const int block = 256;
    const int grid = (nthreads + block - 1) / block;
    qsim8_kernel<<<grid, block, 0, stream>>>(x, w, outp, nsamples);
}

// Round 3
// 24.842 us; speedup vs baseline: 1.5810x; 1.1448x over previous
//
#include <hip/hip_runtime.h>

typedef float v2f __attribute__((ext_vector_type(2)));

#define PI_OVER_4 0.78539816339744830962f

// ---- DPP lane permutes (VALU pipe — no LDS/ds_bpermute traffic) ----
#define DPP_XOR1 0xB1   // quad_perm [1,0,3,2]  : lane ^= 1
#define DPP_XOR2 0x4E   // quad_perm [2,3,0,1]  : lane ^= 2
#define DPP_XOR3 0x1B   // quad_perm [3,2,1,0]  : lane ^= 3
#define DPP_XOR7 0x141  // row_half_mirror      : lane ^= 7

template <int CTRL>
__device__ __forceinline__ float dppf(float v) {
    return __int_as_float(
        __builtin_amdgcn_update_dpp(0, __float_as_int(v), CTRL, 0xF, 0xF, true));
}
template <int CTRL>
__device__ __forceinline__ v2f dpp2(v2f v) {
    v2f r; r.x = dppf<CTRL>(v.x); r.y = dppf<CTRL>(v.y); return r;
}
__device__ __forceinline__ float xor4f(float v) {            // lane ^= 4 (7^3)
    return dppf<DPP_XOR3>(dppf<DPP_XOR7>(v));
}

__device__ __forceinline__ v2f fma2(v2f a, v2f b, v2f c) { return __builtin_elementwise_fma(a, b, c); }
__device__ __forceinline__ v2f splat(float s) { v2f r; r.x = s; r.y = s; return r; }

// Storage in pre-L1-ring coordinates t (qubit q <-> t_q), reg r bits (4..0) = (t3..t7).
// Lane bits are a GF(2) recode of (t0,t1,t2): u2=t0, u1=t1, u0=t1^t2, chosen so the
// three cross-lane gate masks become XOR {7,2,1} — all single-DPP patterns:
//   gates 0&7 (t0,t1 flip)      -> lane^7 (row_half_mirror), gate7 also r^1
//   gate 1    (t1,t2 flip)      -> lane^2 (quad_perm)
//   gate 2    (t2 flip, t3 flip)-> lane^1 (quad_perm), r^16
__global__ __launch_bounds__(256, 4) void qsim8_kernel(
        const float* __restrict__ x, const float* __restrict__ w,
        float* __restrict__ out, int nsamples) {
    const int tid = blockIdx.x * blockDim.x + threadIdx.x;
    const int sample = tid >> 3;
    if (sample >= nsamples) return;
    const int L = threadIdx.x & 7;

    const float4* xv = reinterpret_cast<const float4*>(x + (size_t)sample * 8);
    const float4 xa = xv[0], xb = xv[1];
    const float xs[8] = {xa.x, xa.y, xa.z, xa.w, xb.x, xb.y, xb.z, xb.w};

    // ---- Layer 1 per-qubit factors: RY(x*pi/2 + w_ry) then RZ(w_rz) on |0>
    float chcz[8], chsz[8], shcz[8], shsz[8];
#pragma unroll
    for (int q = 0; q < 8; ++q) {
        const float h = fmaf(xs[q], PI_OVER_4, 0.5f * w[2 * q]);
        const float zz = 0.5f * w[2 * q + 1];
        float sh, ch, sz, cz;
        __sincosf(h, &sh, &ch);
        __sincosf(zz, &sz, &cz);
        chcz[q] = ch * cz; chsz[q] = ch * sz;
        shcz[q] = sh * cz; shsz[q] = sh * sz;
    }

    // ---- lane factor: t0 = u2, t1 = u1, t2 = u1 ^ u0
    float Fr, Fi;
    {
        const int b0 = (L >> 2) & 1;
        const int b1 = (L >> 1) & 1;
        const int b2 = ((L >> 1) ^ L) & 1;
        Fr = b0 ? shcz[0] : chcz[0];
        Fi = b0 ? shsz[0] : -chsz[0];
        const float g1r = b1 ? shcz[1] : chcz[1];
        const float g1i = b1 ? shsz[1] : -chsz[1];
        const float tr = Fr * g1r - Fi * g1i;
        const float ti = Fr * g1i + Fi * g1r;
        const float g2r = b2 ? shcz[2] : chcz[2];
        const float g2i = b2 ? shsz[2] : -chsz[2];
        Fr = tr * g2r - ti * g2i;
        Fi = tr * g2i + ti * g2r;
    }

    // ---- expand product state over qubits 3..7 (r bit4=t3 ... bit0=t7)
    v2f z[32];
    z[0].x = Fr; z[0].y = Fi;
#define EXPAND(Q, M)                                                      \
    {                                                                     \
        const v2f e0  = {chcz[Q], -chsz[Q]};                              \
        const v2f e0f = {chsz[Q],  chcz[Q]};                              \
        const v2f e1  = {shcz[Q],  shsz[Q]};                              \
        const v2f e1f = {-shsz[Q], shcz[Q]};                              \
        _Pragma("unroll")                                                 \
        for (int j = (M) - 1; j >= 0; --j) {                              \
            const v2f a = z[j];                                           \
            z[2 * j + 1] = fma2(splat(a.x), e1, splat(a.y) * e1f);        \
            z[2 * j]     = fma2(splat(a.x), e0, splat(a.y) * e0f);        \
        }                                                                 \
    }
    EXPAND(3, 1)
    EXPAND(4, 2)
    EXPAND(5, 4)
    EXPAND(6, 8)
    EXPAND(7, 16)
#undef EXPAND

    // ---- Layer 2 fused RY(x*pi/2 + w_ry) angles (RZ dropped; L2 ring folded into masks)
    float c2[8], s2[8];
#pragma unroll
    for (int q = 0; q < 8; ++q) {
        const float h = fmaf(xs[q], PI_OVER_4, 0.5f * w[16 + 2 * q]);
        __sincosf(h, &s2[q], &c2[q]);
    }

    const int pl  = __popc(L & 5) & 1;   // t0^t1^t2
    const int p01 = __popc(L & 6) & 1;   // t0^t1

    // ---- fused gates 0 & 7: partner lane L^7, reg pair r^1
    // z[r]   = K1 a + K2 b + s(K3 c + K4 d),  s = (-1)^{popc(r)}, r even
    // z[r+1] = K2 a + K1 b - s(K4 c + K3 d)
    {
        const float c0 = c2[0], c7 = c2[7];
        const float G = (L & 1) ? s2[0] : -s2[0];   // p12 = t1^t2 = u0
        const float H = pl ? s2[7] : -s2[7];
        const float K1 = c7 * c0, K2 = H * G, K3 = c7 * G, K4 = H * c0;
        const float nK3 = -K3, nK4 = -K4;
#pragma unroll
        for (int r = 0; r < 32; r += 2) {
            const bool sp = (__builtin_popcount(r) & 1) == 0;   // compile-time
            const float k3 = sp ? K3 : nK3;
            const float k4 = sp ? K4 : nK4;
            const v2f a = z[r], b = z[r + 1];
            const v2f c = dpp2<DPP_XOR7>(a);
            const v2f d = dpp2<DPP_XOR7>(b);
            v2f za = splat(K1) * a;
            za = fma2(splat(K2), b, za);
            za = fma2(splat(k3), c, za);
            za = fma2(splat(k4), d, za);
            v2f zb = splat(K2) * a;
            zb = fma2(splat(K1), b, zb);
            zb = fma2(splat(-k4), c, zb);
            zb = fma2(splat(-k3), d, zb);
            z[r] = za; z[r + 1] = zb;
        }
    }
    // ---- gate 1: partner lane L^2; sign uniform over r
    {
        const float cc = c2[1];
        const float g = p01 ? s2[1] : -s2[1];
#pragma unroll
        for (int r = 0; r < 32; ++r) {
            const v2f o = dpp2<DPP_XOR2>(z[r]);
            z[r] = fma2(splat(g), o, splat(cc) * z[r]);
        }
    }
    // ---- gate 2: partner lane L^1, reg r^16; sign uniform over r
    {
        const float cc = c2[2];
        const float g = pl ? s2[2] : -s2[2];
#pragma unroll
        for (int r = 0; r < 16; ++r) {
            const v2f oA = dpp2<DPP_XOR1>(z[r + 16]);
            const v2f oB = dpp2<DPP_XOR1>(z[r]);
            z[r]      = fma2(splat(g), oA, splat(cc) * z[r]);
            z[r + 16] = fma2(splat(g), oB, splat(cc) * z[r + 16]);
        }
    }
    // ---- reg-local gates q=3..6: pair r ^ MR, sign = pl ^ par(r & RR)
#define REGGATE(Q, MR, HB, RR)                                                \
    {                                                                         \
        const float cc = c2[Q];                                               \
        const float g = pl ? s2[Q] : -s2[Q];                                  \
        _Pragma("unroll")                                                     \
        for (int r = 0; r < 32; ++r) {                                        \
            if ((r & (HB)) == 0) {                                            \
                const int rB = r ^ (MR);                                      \
                const float sA = (__builtin_popcount(r & (RR)) & 1) ? -g : g; \
                const v2f a = z[r], b = z[rB];                                \
                z[r]  = fma2(splat(sA),  b, splat(cc) * a);                   \
                z[rB] = fma2(splat(-sA), a, splat(cc) * b);                   \
            }                                                                 \
        }                                                                     \
    }
    REGGATE(3, 24, 16, 16)
    REGGATE(4, 12, 8, 24)
    REGGATE(5, 6, 4, 28)
    REGGATE(6, 3, 2, 30)
#undef REGGATE

    // ---- probabilities and folded measurement sums
    float p[32];
#pragma unroll
    for (int r = 0; r < 32; ++r) {
        const v2f q = z[r] * z[r];
        p[r] = q.x + q.y;
    }
    float uu[16], vv[16];
#pragma unroll
    for (int k = 0; k < 16; ++k) {
        uu[k] = p[k] + p[k + 16];
        vv[k] = p[k] - p[k + 16];
    }
    // uu-set masks {0xF, 0xB, 0xA}; vv-set masks {0x5, 0xF, 0x7} — shared trees
    float Pu[8], Mu[8], Mv[8];
#pragma unroll
    for (int j = 0; j < 8; ++j) {
        Pu[j] = uu[2 * j] + uu[2 * j + 1];
        Mu[j] = uu[2 * j] - uu[2 * j + 1];
        Mv[j] = vv[2 * j] - vv[2 * j + 1];
    }
    float PA[4], MB[4], Pv[4], Qv[4];
#pragma unroll
    for (int i = 0; i < 4; ++i) {
        PA[i] = Pu[2 * i] - Pu[2 * i + 1];
        MB[i] = Mu[2 * i] - Mu[2 * i + 1];
        Pv[i] = Mv[2 * i] + Mv[2 * i + 1];
        Qv[i] = Mv[2 * i] - Mv[2 * i + 1];
    }
    const float QA0 = PA[0] + PA[1], QA1 = PA[2] + PA[3];
    const float QB0 = MB[0] + MB[1], QB1 = MB[2] + MB[3];
    const float QF0 = MB[0] - MB[1], QF1 = MB[2] - MB[3];
    const float Pp0 = Pv[0] - Pv[1], Pp1 = Pv[2] - Pv[3];
    const float Qp0 = Qv[0] - Qv[1], Qp1 = Qv[2] - Qv[3];
    const float s0A = QA0 - QA1;
    const float s0B = QB0 - QB1;
    const float s0F = QF0 - QF1;
    const float s15 = Pp0 + Pp1;
    const float s17 = Qp0 + Qp1;
    const float s1F = Qp0 - Qp1;

    const float A  = p01 ? -1.f : 1.f;                  // par(t0^t1) = par(L&6)
    const float Bs = (__popc(L & 7) & 1) ? -1.f : 1.f;  // par(t0^t2) = par(L&7)
    const float D  = (L & 2) ? -1.f : 1.f;              // par(t1)    = par(L&2)
    float acc[8];
    acc[0] = A * s15;
    acc[1] = Bs * s1F;
    acc[2] = D * s1F;
    acc[3] = Bs * s0F;
    acc[4] = D * s17;
    acc[5] = Bs * s0B;
    acc[6] = D * s15;
    acc[7] = Bs * s0A;

    // ---- transpose-reduce (DPP): lane L ends with sum over 8 lanes of acc[L]
    const int h0 = L & 1, h1 = (L >> 1) & 1, h2 = (L >> 2) & 1;
    float t4[4];
#pragma unroll
    for (int k = 0; k < 4; ++k) {
        const float send = h0 ? acc[2 * k] : acc[2 * k + 1];
        const float recv = dppf<DPP_XOR1>(send);
        t4[k] = (h0 ? acc[2 * k + 1] : acc[2 * k]) + recv;
    }
    float t2a[2];
#pragma unroll
    for (int k = 0; k < 2; ++k) {
        const float send = h1 ? t4[2 * k] : t4[2 * k + 1];
        const float recv = dppf<DPP_XOR2>(send);
        t2a[k] = (h1 ? t4[2 * k + 1] : t4[2 * k]) + recv;
    }
    const float send = h2 ? t2a[0] : t2a[1];
    const float recv = xor4f(send);
    const float res = (h2 ? t2a[1] : t2a[0]) + recv;
    out[(size_t)sample * 8 + L] = res;
}

extern "C" void kernel_launch(void* const* d_in, const int* in_sizes, int n_in,
                              void* d_out, int out_size, void* d_ws, size_t ws_size,
                              hipStream_t stream) {
    const float* x = (const float*)d_in[0];
    const float* w = (const float*)d_in[1];
    float* outp = (float*)d_out;
    const int nsamples = in_sizes[0] / 8;
    const int nthreads = nsamples * 8;
    const int block = 256;
    const int grid = (nthreads + block - 1) / block;
    qsim8_kernel<<<grid, block, 0, stream>>>(x, w, outp, nsamples);
}

// Round 5
// 24.226 us; speedup vs baseline: 1.6212x; 1.0254x over previous
//
#include <hip/hip_runtime.h>

typedef float v2f __attribute__((ext_vector_type(2)));

#define PI_OVER_4 0.78539816339744830962f

// ---- DPP lane permutes (VALU pipe) ----
#define DPP_XOR1  0xB1    // quad_perm [1,0,3,2]
#define DPP_XOR2  0x4E    // quad_perm [2,3,0,1]
#define DPP_XOR3  0x1B    // quad_perm [3,2,1,0]
#define DPP_XOR7  0x141   // row_half_mirror
#define DPP_XOR15 0x140   // row_mirror

template <int CTRL>
__device__ __forceinline__ float dppf(float v) {
    return __int_as_float(
        __builtin_amdgcn_update_dpp(0, __float_as_int(v), CTRL, 0xF, 0xF, true));
}
template <int CTRL>
__device__ __forceinline__ v2f dpp2(v2f v) {
    v2f r; r.x = dppf<CTRL>(v.x); r.y = dppf<CTRL>(v.y); return r;
}
__device__ __forceinline__ float xor4f(float v) { return dppf<DPP_XOR3>(dppf<DPP_XOR7>(v)); }
__device__ __forceinline__ float xor8f(float v) { return dppf<DPP_XOR7>(dppf<DPP_XOR15>(v)); }

__device__ __forceinline__ v2f fma2(v2f a, v2f b, v2f c) { return __builtin_elementwise_fma(a, b, c); }
__device__ __forceinline__ v2f splat(float s) { v2f r; r.x = s; r.y = s; return r; }
__device__ __forceinline__ float bperm(int addr, float v) {
    return __int_as_float(__builtin_amdgcn_ds_bpermute(addr, __float_as_int(v)));
}

// 16 lanes/sample. Pre-L1-ring coords t (s = P t); reg r bits (3..0) = (t4..t7).
// Lane bits u (recode): u3=t0, u2=t1, u1=t0^t2, u0=t1^t3
//   => t0=u3, t1=u2, t2=u1^u3, t3=u0^u2.
// Cross-lane gate masks: g0&g7: lane^15 (g7 also r^1); g1: lane^7; g2: lane^3;
// g3: lane^1 & r^8. Reg gates g4,g5,g6: r^12, r^6, r^3.
// Roles: s0=par(u&11)^par(r&15), s1=par(u&12), s2=par(u&6), s3=pv,
// s4=pv^r3, s5=pv^par(r&12), s6=pv^par(r&14), s7=pv^par(r&15); pv=par(u&3).
__global__ __launch_bounds__(256, 5) void qsim8_kernel(
        const float* __restrict__ x, const float* __restrict__ w,
        float* __restrict__ out, int nsamples) {
    const int tid = blockIdx.x * blockDim.x + threadIdx.x;
    const int sample = tid >> 4;
    if (sample >= nsamples) return;
    const int lane = threadIdx.x & 63;
    const int L = lane & 15;
    const int q8 = L & 7;

    // ---- per-lane transcendentals (dedup: 2 sincos/lane instead of 24) ----
    const float xq = x[(size_t)sample * 8 + q8];
    const float wA = (L < 8) ? w[2 * q8] : w[16 + 2 * q8];
    const float wB = w[2 * q8 + 1];
    const float Aang = fmaf(xq, PI_OVER_4, 0.5f * wA);
    const float Bang = 0.5f * wB;
    float sA_, cA_, sB_, cB_;
    __sincosf(Aang, &sA_, &cA_);
    __sincosf(Bang, &sB_, &cB_);
    // L1 products (meaningful in lanes L<8): f0=(chcz,-chsz), f1=(shcz,shsz)
    const float v_chcz = cA_ * cB_, v_chsz = cA_ * sB_;
    const float v_shcz = sA_ * cB_, v_shsz = sA_ * sB_;

    // ---- distribute coefficients within the 16-lane group ----
    const int base = (lane & 48) << 2;
    float lf_chcz[4], lf_chsz[4], lf_shcz[4], lf_shsz[4];   // L1 qubits 0..3 (lane factor)
    float ex_chcz[4], ex_chsz[4], ex_shcz[4], ex_shsz[4];   // L1 qubits 4..7 (expand)
    float c2q[8], s2q[8];                                   // L2 fused RY angles
#pragma unroll
    for (int q = 0; q < 4; ++q) {
        const int ad = base + 4 * q;
        lf_chcz[q] = bperm(ad, v_chcz); lf_chsz[q] = bperm(ad, v_chsz);
        lf_shcz[q] = bperm(ad, v_shcz); lf_shsz[q] = bperm(ad, v_shsz);
    }
#pragma unroll
    for (int q = 0; q < 4; ++q) {
        const int ad = base + 4 * (4 + q);
        ex_chcz[q] = bperm(ad, v_chcz); ex_chsz[q] = bperm(ad, v_chsz);
        ex_shcz[q] = bperm(ad, v_shcz); ex_shsz[q] = bperm(ad, v_shsz);
    }
#pragma unroll
    for (int q = 0; q < 8; ++q) {
        const int ad = base + 4 * (8 + q);
        c2q[q] = bperm(ad, cA_); s2q[q] = bperm(ad, sA_);
    }

    // ---- lane factor: qubits 0..3 selected by t-bits of this lane ----
    const int b0 = (L >> 3) & 1;
    const int b1 = (L >> 2) & 1;
    const int b2 = ((L >> 1) ^ (L >> 3)) & 1;
    const int b3 = (L ^ (L >> 2)) & 1;
    float Fr = b0 ? lf_shcz[0] : lf_chcz[0];
    float Fi = b0 ? lf_shsz[0] : -lf_chsz[0];
    {
        const float g1r = b1 ? lf_shcz[1] : lf_chcz[1];
        const float g1i = b1 ? lf_shsz[1] : -lf_chsz[1];
        const float tr = Fr * g1r - Fi * g1i;
        const float ti = Fr * g1i + Fi * g1r;
        const float g2r = b2 ? lf_shcz[2] : lf_chcz[2];
        const float g2i = b2 ? lf_shsz[2] : -lf_chsz[2];
        const float ur = tr * g2r - ti * g2i;
        const float ui = tr * g2i + ti * g2r;
        const float g3r = b3 ? lf_shcz[3] : lf_chcz[3];
        const float g3i = b3 ? lf_shsz[3] : -lf_chsz[3];
        Fr = ur * g3r - ui * g3i;
        Fi = ur * g3i + ui * g3r;
    }

    // ---- expand product state over qubits 4..7 (r bit3=t4 ... bit0=t7) ----
    v2f z[16];
    z[0].x = Fr; z[0].y = Fi;
#define EXPAND(Qi, M_)                                                    \
    {                                                                     \
        const v2f e0  = {ex_chcz[Qi], -ex_chsz[Qi]};                      \
        const v2f e0f = {ex_chsz[Qi],  ex_chcz[Qi]};                      \
        const v2f e1  = {ex_shcz[Qi],  ex_shsz[Qi]};                      \
        const v2f e1f = {-ex_shsz[Qi], ex_shcz[Qi]};                      \
        _Pragma("unroll")                                                 \
        for (int j = (M_) - 1; j >= 0; --j) {                             \
            const v2f a = z[j];                                           \
            z[2 * j + 1] = fma2(splat(a.x), e1, splat(a.y) * e1f);        \
            z[2 * j]     = fma2(splat(a.x), e0, splat(a.y) * e0f);        \
        }                                                                 \
    }
    EXPAND(0, 1)
    EXPAND(1, 2)
    EXPAND(2, 4)
    EXPAND(3, 8)
#undef EXPAND

    const int pv = __popc(L & 3) & 1;

    // ---- fused gates 0 & 7 (both pair along lane^15; g7 also r^1) ----
    // a=z[u,r], b=z[u,r+1], c=z[u^15,r], d=z[u^15,r+1]:
    //   z'[r]   = K1 a + HG b + (±GC) c + (±HB) d
    //   z'[r+1] = HG a + K1 b - (±HB) c - (±GC) d      (± = (-1)^par(r))
    {
        const float c0 = c2q[0], s0 = s2q[0], c7 = c2q[7], s7 = s2q[7];
        const int pu = __popc(L & 11) & 1;
        const float G = pu ? s0 : -s0;
        const float H = pv ? s7 : -s7;
        const float K1 = c7 * c0, HG = H * G, GC = G * c7, HB = H * c0;
#pragma unroll
        for (int r = 0; r < 16; r += 2) {
            const bool ev = (__builtin_popcount(r) & 1) == 0;   // compile-time
            const float gc = ev ? GC : -GC;
            const float hb = ev ? HB : -HB;
            const v2f a = z[r], b = z[r + 1];
            const v2f c = dpp2<DPP_XOR15>(a);
            const v2f d = dpp2<DPP_XOR15>(b);
            v2f za = splat(K1) * a;
            za = fma2(splat(HG), b, za);
            za = fma2(splat(gc), c, za);
            za = fma2(splat(hb), d, za);
            v2f zb = splat(HG) * a;
            zb = fma2(splat(K1), b, zb);
            zb = fma2(splat(-hb), c, zb);
            zb = fma2(splat(-gc), d, zb);
            z[r] = za; z[r + 1] = zb;
        }
    }
    // ---- gate 1: lane^7; role par(u&12) ----
    {
        const float cc = c2q[1];
        const float g = (__popc(L & 12) & 1) ? s2q[1] : -s2q[1];
#pragma unroll
        for (int r = 0; r < 16; ++r) {
            const v2f o = dpp2<DPP_XOR7>(z[r]);
            z[r] = fma2(splat(g), o, splat(cc) * z[r]);
        }
    }
    // ---- gate 2: lane^3; role par(u&6) ----
    {
        const float cc = c2q[2];
        const float g = (__popc(L & 6) & 1) ? s2q[2] : -s2q[2];
#pragma unroll
        for (int r = 0; r < 16; ++r) {
            const v2f o = dpp2<DPP_XOR3>(z[r]);
            z[r] = fma2(splat(g), o, splat(cc) * z[r]);
        }
    }
    // ---- gate 3: lane^1 & r^8; role pv ----
    {
        const float cc = c2q[3];
        const float g = pv ? s2q[3] : -s2q[3];
#pragma unroll
        for (int r = 0; r < 8; ++r) {
            const v2f oA = dpp2<DPP_XOR1>(z[r + 8]);
            const v2f oB = dpp2<DPP_XOR1>(z[r]);
            z[r]     = fma2(splat(g), oA, splat(cc) * z[r]);
            z[r + 8] = fma2(splat(g), oB, splat(cc) * z[r + 8]);
        }
    }
    // ---- reg-local gates 4..6: pair r^MR; role pv ^ par(r&RR) ----
#define REGGATE(Q, MR, HBIT, RR)                                              \
    {                                                                         \
        const float cc = c2q[Q];                                              \
        const float g = pv ? s2q[Q] : -s2q[Q];                                \
        _Pragma("unroll")                                                     \
        for (int r = 0; r < 16; ++r) {                                        \
            if ((r & (HBIT)) == 0) {                                          \
                const int rB = r ^ (MR);                                      \
                const float sA = (__builtin_popcount(r & (RR)) & 1) ? -g : g; \
                const v2f a = z[r], b = z[rB];                                \
                z[r]  = fma2(splat(sA),  b, splat(cc) * a);                   \
                z[rB] = fma2(splat(-sA), a, splat(cc) * b);                   \
            }                                                                 \
        }                                                                     \
    }
    REGGATE(4, 12, 8, 8)
    REGGATE(5, 6, 4, 12)
    REGGATE(6, 3, 2, 14)
#undef REGGATE

    // ---- probabilities and 5 masked register sums S_m, m in {5,7,10,11,15} ----
    float p[16];
#pragma unroll
    for (int r = 0; r < 16; ++r) {
        const v2f t = z[r] * z[r];
        p[r] = t.x + t.y;
    }
    float P[8], M[8];
#pragma unroll
    for (int j = 0; j < 8; ++j) {
        P[j] = p[2 * j] + p[2 * j + 1];
        M[j] = p[2 * j] - p[2 * j + 1];
    }
    float MP[4], MM[4], PM[4];
#pragma unroll
    for (int i = 0; i < 4; ++i) {
        MP[i] = M[2 * i] + M[2 * i + 1];
        MM[i] = M[2 * i] - M[2 * i + 1];
        PM[i] = P[2 * i] - P[2 * i + 1];
    }
    const float MPM0 = MP[0] - MP[1], MPM1 = MP[2] - MP[3];
    const float MMM0 = MM[0] - MM[1], MMM1 = MM[2] - MM[3];
    const float MMP0 = MM[0] + MM[1], MMP1 = MM[2] + MM[3];
    const float PMP0 = PM[0] + PM[1], PMP1 = PM[2] + PM[3];
    const float S5  = MPM0 + MPM1;
    const float S7  = MMM0 + MMM1;
    const float S15 = MMM0 - MMM1;
    const float S11 = MMP0 - MMP1;
    const float S10 = PMP0 - PMP1;

    // ---- lane sign prefactors; C_i lane masks: {9,7,1,2,1,2,1,2} ----
    const float sg1 = (L & 1) ? -1.f : 1.f;
    const float sg2 = (L & 2) ? -1.f : 1.f;
    const float sg9 = (__popc(L & 9) & 1) ? -1.f : 1.f;
    const float sg7 = (__popc(L & 7) & 1) ? -1.f : 1.f;
    float acc[8];
    acc[0] = sg9 * S5;
    acc[1] = sg7 * S15;
    acc[2] = sg1 * S15;
    acc[3] = sg2 * S15;
    acc[4] = sg1 * S7;
    acc[5] = sg2 * S11;
    acc[6] = sg1 * S5;
    acc[7] = sg2 * S10;

    // ---- transpose-reduce over 16 lanes (DPP); lane L<8 ends with sum of acc[L] ----
    const int h0 = L & 1, h1 = (L >> 1) & 1, h2 = (L >> 2) & 1;
    float t4a[4];
#pragma unroll
    for (int k = 0; k < 4; ++k) {
        const float send = h0 ? acc[2 * k] : acc[2 * k + 1];
        const float recv = dppf<DPP_XOR1>(send);
        t4a[k] = (h0 ? acc[2 * k + 1] : acc[2 * k]) + recv;
    }
    float t2a[2];
#pragma unroll
    for (int k = 0; k < 2; ++k) {
        const float send = h1 ? t4a[2 * k] : t4a[2 * k + 1];
        const float recv = dppf<DPP_XOR2>(send);
        t2a[k] = (h1 ? t4a[2 * k + 1] : t4a[2 * k]) + recv;
    }
    {
        const float send = h2 ? t2a[0] : t2a[1];
        const float recv = xor4f(send);
        float res = (h2 ? t2a[1] : t2a[0]) + recv;
        res += xor8f(res);   // fold the two u3-halves
        if (L < 8) out[(size_t)sample * 8 + L] = res;
    }
}

extern "C" void kernel_launch(void* const* d_in, const int* in_sizes, int n_in,
                              void* d_out, int out_size, void* d_ws, size_t ws_size,
                              hipStream_t stream) {
    const float* x = (const float*)d_in[0];
    const float* w = (const float*)d_in[1];
    float* outp = (float*)d_out;
    const int nsamples = in_sizes[0] / 8;
    const int nthreads = nsamples * 16;
    const int block = 256;
    const int grid = (nthreads + block - 1) / block;
    qsim8_kernel<<<grid, block, 0, stream>>>(x, w, outp, nsamples);
}